// Round 2
// baseline (565.684 us; speedup 1.0000x reference)
//
#include <hip/hip_runtime.h>
#include <cstdint>
#include <cstddef>

// Problem constants (fixed by the reference setup)
#define BS    2048
#define DIN   1024
#define DOUT  1024
#define SSEG  10
#define NPAR  30720          // dout * S * 3
#define NPK   20480          // packed smooth cols: S*DOUT*2 (ch1,ch2)
#define NCOL2 21504          // NPK + DOUT (norm appended)
#define NLG   10240          // S * DOUT logit columns (channel 0)
#define TAU   5e-5f          // near-boundary radius (~10x worst fp32-pipeline kp error)
#define WL_CAP 1048576u      // worklist capacity (entries)

// prep kernel regions
#define NB_SPLIT 2048        // x fp16x2 split blocks
#define NB_NORM  1024        // norm_W transpose blocks
#define NB_TRW   2560        // param_W transpose blocks (80 x 32)

// unified GEMM grid: 320 logit blocks + 672 smooth blocks, 256x256 tiles.
// mt = bid & 7 pins each XCD (bid%8) to ONE 256-row A panel -> A L2-resident.
#define GEMM_BLKS 992

typedef _Float16 half_t;
typedef __attribute__((ext_vector_type(8))) _Float16 half8;
typedef __attribute__((ext_vector_type(4))) _Float16 half4;
typedef __attribute__((ext_vector_type(2))) _Float16 half2v;
typedef __attribute__((ext_vector_type(4))) float   floatx4;

__device__ __forceinline__ void gload16(const void* g, void* l) {
  __builtin_amdgcn_global_load_lds(
      (const __attribute__((address_space(1))) void*)g,
      (__attribute__((address_space(3))) void*)l, 16, 0, 0);
}

// ---------------------------------------------------------------------------
__global__ void k_zero(unsigned* c) { if (threadIdx.x == 0) *c = 0; }

// ---------------------------------------------------------------------------
// Prep (3 regions):
//  [0, 2048):        x -> xh/xl fp16x2 split (+ zero worklist counter)
//  [2048, 3072):     norm_W transpose -> wsm rows [NPK, NCOL2)
//  [3072, 5632):     param_W 32k x 384col tiles ->
//                      wsm (ch1/ch2 fp16), wh/wlo (fp16x2 of 32w), wlt (fp32)
// ---------------------------------------------------------------------------
__global__ __launch_bounds__(256) void k_prep(const float* __restrict__ x,
                                              half_t* __restrict__ xh,
                                              half_t* __restrict__ xl,
                                              const float* __restrict__ nW,
                                              const float* __restrict__ pW,
                                              half_t* __restrict__ wsm,
                                              half_t* __restrict__ wh,
                                              half_t* __restrict__ wlo,
                                              float* __restrict__ wlt,
                                              unsigned* __restrict__ cnt) {
  __shared__ float tile[32][384];              // 48 KB (transw region)
  int bid = blockIdx.x;
  int tid = threadIdx.x;

  if (bid < NB_SPLIT) {
    if (bid == 0 && tid == 0) *cnt = 0;
    int i = bid * 256 + tid;                   // float4 groups over BS*DIN
    floatx4 v = ((const floatx4*)x)[i];
    half4 h, l;
    #pragma unroll
    for (int c = 0; c < 4; c++) { h[c] = (half_t)v[c]; l[c] = (half_t)(v[c] - (float)h[c]); }
    ((half4*)xh)[i] = h;
    ((half4*)xl)[i] = l;
    return;
  }

  if (bid < NB_SPLIT + NB_NORM) {
    int b2 = bid - NB_SPLIT;                   // 0..1023
    int col0 = (b2 & 31) * 32;
    int k0   = (b2 >> 5) * 32;
    int tx = tid & 31;
    int ty = tid >> 5;
    float* t33 = &tile[0][0];                  // reuse LDS as 32x33
    #pragma unroll
    for (int r = ty; r < 32; r += 8)
      t33[r * 33 + tx] = nW[(size_t)(k0 + r) * DOUT + col0 + tx];
    __syncthreads();
    #pragma unroll
    for (int r = ty; r < 32; r += 8)
      wsm[(size_t)(col0 + r + NPK) * DIN + k0 + tx] = (half_t)t33[tx * 33 + r];
    return;
  }

  // ---- transw region ----
  int b3 = bid - NB_SPLIT - NB_NORM;           // 0..2559
  int bx = b3 % 80;                            // 384-col group
  int k0 = (b3 / 80) * 32;                     // k tile
  int s  = bx >> 3;                            // logit segment
  int d0 = (bx & 7) * 128;

  const float* sb = pW + (size_t)k0 * NPAR + bx * 384;
  for (int i = tid; i < 32 * 96; i += 256) {   // 12 coalesced float4/thread
    int r = i / 96, q = i - r * 96;
    ((floatx4*)&tile[r][0])[q] = ((const floatx4*)(sb + (size_t)r * NPAR))[q];
  }
  __syncthreads();

  for (int ci = tid; ci < 3072; ci += 256) {
    if (ci < 1024) {                           // wsm ch1/ch2: 256 rows x 4 chunks
      int rl = ci >> 2, kc = ci & 3;
      int jj = rl >> 1, cbit = rl & 1;
      int col = 3 * jj + 1 + cbit;
      half8 v;
      #pragma unroll
      for (int m = 0; m < 8; m++) v[m] = (half_t)tile[kc * 8 + m][col];
      *(half8*)(wsm + (size_t)(s * 2048 + 2 * (d0 + jj) + cbit) * DIN + k0 + kc * 8) = v;
    } else if (ci < 1536) {                    // wh: 128 rows x 4 chunks
      int u = ci - 1024;
      int jj = u >> 2, kc = u & 3;
      half8 v;
      #pragma unroll
      for (int m = 0; m < 8; m++) v[m] = (half_t)(tile[kc * 8 + m][3 * jj] * 32.0f);
      *(half8*)(wh + (size_t)(s * 1024 + d0 + jj) * DIN + k0 + kc * 8) = v;
    } else if (ci < 2048) {                    // wlo: 128 rows x 4 chunks
      int u = ci - 1536;
      int jj = u >> 2, kc = u & 3;
      half8 v;
      #pragma unroll
      for (int m = 0; m < 8; m++) {
        float raw = tile[kc * 8 + m][3 * jj] * 32.0f;   // exact pow2 scale
        half_t h = (half_t)raw;
        v[m] = (half_t)(raw - (float)h);
      }
      *(half8*)(wlo + (size_t)(s * 1024 + d0 + jj) * DIN + k0 + kc * 8) = v;
    } else {                                   // wlt fp32: 128 rows x 8 chunks
      int u = ci - 2048;
      int jj = u >> 3, kc = u & 7;
      floatx4 v;
      #pragma unroll
      for (int m = 0; m < 4; m++) v[m] = tile[kc * 4 + m][3 * jj];
      *(floatx4*)(wlt + (size_t)(s * 1024 + d0 + jj) * DIN + k0 + kc * 4) = v;
    }
  }
}

// ---------------------------------------------------------------------------
// Unified GEMM, 256x256 tile, 512 threads (8 waves 2x4), per-wave 128x64 out.
//
// mode 0 (bid<320, logit): per 32-k chunk stage {xh,xl,wh,wlo} (4x16KB) ONCE
//   and run 3 products (xh*wh + xl*wh + xh*wlo) = 96 MFMA/wave from it.
//   LDS: 2 x 64KB chunk-set double buffer. One barrier per chunk; counted
//   vmcnt(0) at chunk end (loads issued a full chunk (~900cy) earlier).
// mode 1 (bid>=320, smooth): P = xh*wsm^T; 4-deep {A,B} ring (4x32KB),
//   stage 3 tiles ahead, steady-state vmcnt(8), one barrier per kt.
//
// XCD locality: mt = bid&7 (bid%8 = XCD) -> each XCD reads ONE 256-row
// xh/xl panel (1 MB, L2-resident); B panels stream from LLC once per XCD.
//
// LDS tile layout (16KB): 128 lines x 128B; line L = rows {2L,2L+1} x 32 k.
// 16B slot s of line L holds global chunk s^(L&7) (XOR swizzle on both the
// gload source address and the ds_read address -> conflict-free).
// ---------------------------------------------------------------------------
__global__ __launch_bounds__(512, 2) void k_gemm2(
    const half_t* __restrict__ xh, const half_t* __restrict__ xl,
    const half_t* __restrict__ wh, const half_t* __restrict__ wlo,
    const half_t* __restrict__ wsm,
    float* __restrict__ Lg, half_t* __restrict__ P,
    const float* __restrict__ pb, const float* __restrict__ nb) {
  __shared__ __attribute__((aligned(128))) char lds[131072];

  int bid = blockIdx.x;
  int tid = threadIdx.x;
  int w = tid >> 6, l = tid & 63;
  int wr = w >> 2, wc = w & 3;                 // wave grid 2 (rows) x 4 (cols)
  int l15 = l & 15, quad = l >> 4;

  int mode, mt, nt;
  if (bid < 320) { mode = 0; mt = bid & 7; nt = bid >> 3; }   // 8 x 40
  else { int s2 = bid - 320; mode = 1; mt = s2 & 7; nt = s2 >> 3; } // 8 x 84
  int m0 = mt * 256, n0 = nt * 256;

  // staging geometry: lane l covers line (l>>3), linear slot (l&7); source
  // chunk pre-swizzled: s' = (l&7)^(l>>3)  (rule: swizzle both sides).
  int sp = (l & 7) ^ ((l >> 3) & 7);
  int srowA = m0 + w * 32 + 2 * (l >> 3) + (sp >> 2);
  int srowB = n0 + w * 32 + 2 * (l >> 3) + (sp >> 2);
  int scol = (sp & 3) * 8;

  // fragment read: row base+l15 -> line (l15>>1), half l15&1, chunk quad;
  // swizzled slot = (((l15&1)<<2)|quad) ^ (l15>>1).
  int lofs = (l15 >> 1) * 128 + (((((l15 & 1) << 2) | quad) ^ (l15 >> 1)) << 4);

  floatx4 acc[8][4] = {};

  if (mode == 0) {
    // ---- logit: 32 chunks, dbuf of 64KB chunk-sets ----
    auto stage0 = [&](int c) {                 // 8 gload16 per wave
      char* base = lds + ((c & 1) * 65536) + w * 2048;
      const half_t* ga = xh + (size_t)srowA * DIN + c * 32 + scol;
      const half_t* gx = xl + (size_t)srowA * DIN + c * 32 + scol;
      const half_t* gh = wh + (size_t)srowB * DIN + c * 32 + scol;
      const half_t* gl = wlo + (size_t)srowB * DIN + c * 32 + scol;
      gload16(ga, base);                gload16(ga + 16 * DIN, base + 1024);
      gload16(gx, base + 16384);        gload16(gx + 16 * DIN, base + 16384 + 1024);
      gload16(gh, base + 32768);        gload16(gh + 16 * DIN, base + 32768 + 1024);
      gload16(gl, base + 49152);        gload16(gl + 16 * DIN, base + 49152 + 1024);
    };

    stage0(0);
    asm volatile("s_waitcnt vmcnt(0)" ::: "memory");
    __builtin_amdgcn_s_barrier();

    for (int c = 0; c < 32; ++c) {
      const char* base = lds + (c & 1) * 65536;
      const char* aXH = base + wr * 8192 + lofs;
      const char* aXL = base + 16384 + wr * 8192 + lofs;
      const char* bWH = base + 32768 + wc * 4096 + lofs;
      const char* bWL = base + 49152 + wc * 4096 + lofs;
      if (c + 1 < 32) stage0(c + 1);

      half8 bh[4], bl[4], a0[4], a1[4], x0[4], x1[4];
      #pragma unroll
      for (int ni = 0; ni < 4; ni++) bh[ni] = *(const half8*)(bWH + ni * 1024);
      #pragma unroll
      for (int mi = 0; mi < 4; mi++) a0[mi] = *(const half8*)(aXH + mi * 1024);
      #pragma unroll
      for (int mi = 0; mi < 4; mi++) a1[mi] = *(const half8*)(aXH + 4096 + mi * 1024);
      #pragma unroll
      for (int mi = 0; mi < 4; mi++)
        #pragma unroll
        for (int ni = 0; ni < 4; ni++) {
          acc[mi][ni]     = __builtin_amdgcn_mfma_f32_16x16x32_f16(a0[mi], bh[ni], acc[mi][ni], 0, 0, 0);
          acc[4 + mi][ni] = __builtin_amdgcn_mfma_f32_16x16x32_f16(a1[mi], bh[ni], acc[4 + mi][ni], 0, 0, 0);
        }
      #pragma unroll
      for (int mi = 0; mi < 4; mi++) x0[mi] = *(const half8*)(aXL + mi * 1024);
      #pragma unroll
      for (int mi = 0; mi < 4; mi++) x1[mi] = *(const half8*)(aXL + 4096 + mi * 1024);
      #pragma unroll
      for (int mi = 0; mi < 4; mi++)
        #pragma unroll
        for (int ni = 0; ni < 4; ni++) {
          acc[mi][ni]     = __builtin_amdgcn_mfma_f32_16x16x32_f16(x0[mi], bh[ni], acc[mi][ni], 0, 0, 0);
          acc[4 + mi][ni] = __builtin_amdgcn_mfma_f32_16x16x32_f16(x1[mi], bh[ni], acc[4 + mi][ni], 0, 0, 0);
        }
      #pragma unroll
      for (int ni = 0; ni < 4; ni++) bl[ni] = *(const half8*)(bWL + ni * 1024);
      #pragma unroll
      for (int mi = 0; mi < 4; mi++)
        #pragma unroll
        for (int ni = 0; ni < 4; ni++) {
          acc[mi][ni]     = __builtin_amdgcn_mfma_f32_16x16x32_f16(a0[mi], bl[ni], acc[mi][ni], 0, 0, 0);
          acc[4 + mi][ni] = __builtin_amdgcn_mfma_f32_16x16x32_f16(a1[mi], bl[ni], acc[4 + mi][ni], 0, 0, 0);
        }
      if (c + 1 < 32) {
        __builtin_amdgcn_sched_barrier(0);     // pin chunk body (rule #18)
        asm volatile("s_waitcnt vmcnt(0)" ::: "memory");
        __builtin_amdgcn_s_barrier();
      }
    }
  } else {
    // ---- smooth: 32 kts, 4-deep {A,B} ring, counted vmcnt ----
    auto stage1 = [&](int kt) {                // 4 gload16 per wave
      char* base = lds + ((kt & 3) * 32768) + w * 2048;
      const half_t* ga = xh + (size_t)srowA * DIN + kt * 32 + scol;
      const half_t* gb = wsm + (size_t)srowB * DIN + kt * 32 + scol;
      gload16(ga, base);            gload16(ga + 16 * DIN, base + 1024);
      gload16(gb, base + 16384);    gload16(gb + 16 * DIN, base + 16384 + 1024);
    };

    stage1(0); stage1(1); stage1(2);
    asm volatile("s_waitcnt vmcnt(8)" ::: "memory");
    __builtin_amdgcn_s_barrier();

    for (int kt = 0; kt < 32; ++kt) {
      const char* base = lds + (kt & 3) * 32768;
      const char* a = base + wr * 8192 + lofs;
      const char* b = base + 16384 + wc * 4096 + lofs;
      if (kt + 3 < 32) stage1(kt + 3);

      half8 bf[4], af[4], ag[4];
      #pragma unroll
      for (int ni = 0; ni < 4; ni++) bf[ni] = *(const half8*)(b + ni * 1024);
      #pragma unroll
      for (int mi = 0; mi < 4; mi++) af[mi] = *(const half8*)(a + mi * 1024);
      #pragma unroll
      for (int mi = 0; mi < 4; mi++) ag[mi] = *(const half8*)(a + 4096 + mi * 1024);
      #pragma unroll
      for (int mi = 0; mi < 4; mi++)
        #pragma unroll
        for (int ni = 0; ni < 4; ni++) {
          acc[mi][ni]     = __builtin_amdgcn_mfma_f32_16x16x32_f16(af[mi], bf[ni], acc[mi][ni], 0, 0, 0);
          acc[4 + mi][ni] = __builtin_amdgcn_mfma_f32_16x16x32_f16(ag[mi], bf[ni], acc[4 + mi][ni], 0, 0, 0);
        }
      if (kt < 29) {
        __builtin_amdgcn_sched_barrier(0);
        asm volatile("s_waitcnt vmcnt(8)" ::: "memory");
        __builtin_amdgcn_s_barrier();
      } else if (kt == 29) {
        __builtin_amdgcn_sched_barrier(0);
        asm volatile("s_waitcnt vmcnt(4)" ::: "memory");
        __builtin_amdgcn_s_barrier();
      } else if (kt == 30) {
        __builtin_amdgcn_sched_barrier(0);
        asm volatile("s_waitcnt vmcnt(0)" ::: "memory");
        __builtin_amdgcn_s_barrier();
      }
    }
  }

  // ---- epilogue ----
  int rbase = m0 + wr * 128 + quad * 4;
  int cbase = n0 + wc * 64 + l15;
  if (mode == 0) {
    #pragma unroll
    for (int ni = 0; ni < 4; ni++) {
      int col = cbase + ni * 16;               // packed s*1024+d
      float bias = pb[(col >> 10) * 3072 + (col & 1023) * 3];
      #pragma unroll
      for (int mi = 0; mi < 8; mi++) {
        int row = rbase + mi * 16;
        floatx4 v = acc[mi][ni];
        #pragma unroll
        for (int r = 0; r < 4; r++)
          Lg[(size_t)(row + r) * NLG + col] = v[r] * 0.03125f + bias;
      }
    }
  } else {
    #pragma unroll
    for (int ni = 0; ni < 4; ni++) {
      int col = cbase + ni * 16;
      float bias;
      if (col < NPK) {
        int s = col >> 11, rem = col & 2047;
        bias = pb[s * 3072 + 3 * (rem >> 1) + 1 + (rem & 1)];
      } else {
        bias = nb[col - NPK];
      }
      #pragma unroll
      for (int mi = 0; mi < 8; mi++) {
        int row = rbase + mi * 16;
        floatx4 v = acc[mi][ni];
        #pragma unroll
        for (int r = 0; r < 4; r++)
          P[(size_t)(row + r) * NCOL2 + col] = (half_t)(v[r] + bias);
      }
    }
  }
}

// ---------------------------------------------------------------------------
// fp32 formula; mind = min_j |t - kp[j]| for near-boundary flagging
// ---------------------------------------------------------------------------
__device__ __forceinline__ float spiking_eval(const float* p, float tt, float* mind) {
  float mx = -1e30f;
  #pragma unroll
  for (int s = 0; s < SSEG; s++) mx = fmaxf(mx, p[3 * s]);
  float ew[10], wsum = 0.0f;
  #pragma unroll
  for (int s = 0; s < SSEG; s++) { ew[s] = __expf(p[3 * s] - mx); wsum += ew[s]; }
  float inv = 1.0f / wsum;

  float kp[11];
  kp[0] = -1.0f;
  float cum = 0.0f, md = 1e30f;
  #pragma unroll
  for (int s = 0; s < SSEG; s++) {
    cum += ew[s] * inv;
    kp[s + 1] = cum * 2.0f - 1.0f;
    md = fminf(md, fabsf(tt - kp[s + 1]));
  }
  *mind = md;

  float vf[10], resid[10];
  float lm = 0.0f, rm = 0.0f, integ = 0.0f;
  #pragma unroll
  for (int s = 0; s < SSEG; s++) {
    float p1 = p[3 * s + 1], p2 = p[3 * s + 2];
    float e2 = __expf(2.0f * fabsf(p1));
    float th = copysignf(1.0f - 2.0f / (e2 + 1.0f), p1);
    resid[s] = th * tt + p2;
    float st = kp[s], en = kp[s + 1];
    bool v = ((tt >= st) && (tt < en)) || ((tt == 1.0f) && (en == 1.0f));
    float vv = v ? 1.0f : 0.0f;
    vf[s] = vv;
    lm += (tt - st) * vv;
    rm += (en - tt) * vv;
    integ += 0.5f * th * (en * en - st * st) + p2 * (ew[s] * inv);
  }
  float resLV = 0.0f, resV = 0.0f, resRV = 0.0f;
  #pragma unroll
  for (int s = 0; s < SSEG; s++) {
    float lv = (s == 0) ? vf[0] : vf[s - 1];
    float rv = (s == 9) ? vf[9] : vf[s + 1];
    resLV += resid[s] * lv;
    resV  += resid[s] * vf[s];
    resRV += resid[s] * rv;
  }
  float lw = 1.0f / (1.0f + __expf(50.0f * lm));
  float rw = 1.0f / (1.0f + __expf(50.0f * rm));
  float swt = 1.0f - lw - rw;
  return lw * resLV + swt * resV + rw * resRV - 0.5f * integ + p[30];
}

// ---------------------------------------------------------------------------
// Pointwise: logits fp32 from Lg, ch1/2+norm fp16 from P. Flags near-boundary.
// ---------------------------------------------------------------------------
__global__ __launch_bounds__(256) void k_pointwise(const half_t* __restrict__ P,
                                                   const float* __restrict__ Lg,
                                                   const float* __restrict__ t,
                                                   float* __restrict__ out,
                                                   unsigned* __restrict__ cnt,
                                                   unsigned* __restrict__ wl,
                                                   unsigned cap) {
  __shared__ __attribute__((aligned(16))) half_t sp[SSEG * 512];
  int b = blockIdx.x, dg = blockIdx.y, tid = threadIdx.x;
  const half_t* Pb = P + (size_t)b * NCOL2;
  for (int i = tid; i < SSEG * 64; i += 256) {     // 640 x 16B
    int s = i >> 6, e = i & 63;
    ((uint4*)sp)[(s << 6) + e] = ((const uint4*)(Pb + s * 2048 + dg * 512))[e];
  }
  float tt = t[b];
  float nt = (float)Pb[NPK + dg * 256 + tid];
  const float* Lb = Lg + (size_t)b * NLG + dg * 256 + tid;
  __syncthreads();

  float p[31];
  #pragma unroll
  for (int s = 0; s < SSEG; s++) {
    p[3 * s] = Lb[s * 1024];                       // accurate logit (bias incl.)
    half2v hv = ((const half2v*)sp)[s * 256 + tid];  // 4B/lane, conflict-free
    p[3 * s + 1] = (float)hv.x;
    p[3 * s + 2] = (float)hv.y;
  }
  p[30] = nt;
  float mind;
  float r = spiking_eval(p, tt, &mind);
  int d = dg * 256 + tid;
  out[(size_t)b * DOUT + d] = r;
  if (wl != nullptr && mind < TAU) {
    unsigned idx = atomicAdd(cnt, 1u);
    if (idx < cap) wl[idx] = ((unsigned)b << 10) | (unsigned)d;
  }
}

// ---------------------------------------------------------------------------
// Fallback: fused naive fp32 + flagging (tiny-workspace insurance)
// ---------------------------------------------------------------------------
__global__ __launch_bounds__(256) void k_naive(const float* __restrict__ x,
                                               const float* __restrict__ t,
                                               const float* __restrict__ pW,
                                               const float* __restrict__ pb,
                                               const float* __restrict__ nW,
                                               const float* __restrict__ nb,
                                               float* __restrict__ out,
                                               unsigned* __restrict__ cnt,
                                               unsigned* __restrict__ wl,
                                               unsigned cap) {
  __shared__ float xs[DIN];
  int b = blockIdx.x, dg = blockIdx.y, tid = threadIdx.x;
  for (int i = tid; i < DIN; i += 256) xs[i] = x[(size_t)b * DIN + i];
  __syncthreads();
  int d = dg * 256 + tid;
  float acc[31];
  #pragma unroll
  for (int i = 0; i < 31; i++) acc[i] = 0.0f;
  for (int k = 0; k < DIN; k++) {
    float xv = xs[k];
    const float* wr = pW + (size_t)k * NPAR + 3 * d;
    #pragma unroll
    for (int s = 0; s < SSEG; s++) {
      acc[3 * s]     += xv * wr[s * 3072];
      acc[3 * s + 1] += xv * wr[s * 3072 + 1];
      acc[3 * s + 2] += xv * wr[s * 3072 + 2];
    }
    acc[30] += xv * nW[(size_t)k * DOUT + d];
  }
  #pragma unroll
  for (int s = 0; s < SSEG; s++) {
    acc[3 * s]     += pb[s * 3072 + 3 * d];
    acc[3 * s + 1] += pb[s * 3072 + 3 * d + 1];
    acc[3 * s + 2] += pb[s * 3072 + 3 * d + 2];
  }
  acc[30] += nb[d];
  float mind;
  float r = spiking_eval(acc, t[b], &mind);
  out[(size_t)b * DOUT + d] = r;
  if (wl != nullptr && mind < TAU) {
    unsigned idx = atomicAdd(cnt, 1u);
    if (idx < cap) wl[idx] = ((unsigned)b << 10) | (unsigned)d;
  }
}

// ---------------------------------------------------------------------------
// f64 redo: one wave per flagged (b,d). haveP: coalesced WLt logit weights +
// fp16 smooth channels from P. !haveP: pW gather (fallback path).
// ---------------------------------------------------------------------------
__global__ __launch_bounds__(256) void k_redo(const float* __restrict__ x,
                                              const float* __restrict__ t,
                                              const float* __restrict__ pW,
                                              const float* __restrict__ pb,
                                              const float* __restrict__ nW,
                                              const float* __restrict__ nb,
                                              const half_t* __restrict__ P,
                                              const float* __restrict__ WLt,
                                              int haveP,
                                              const unsigned* __restrict__ cnt,
                                              const unsigned* __restrict__ wl,
                                              unsigned cap,
                                              float* __restrict__ out) {
  unsigned n = *cnt;
  if (n > cap) n = cap;
  int lane = threadIdx.x & 63;
  unsigned wave = (blockIdx.x * 256 + threadIdx.x) >> 6;
  unsigned nwaves = (gridDim.x * 256) >> 6;

  for (unsigned e = wave; e < n; e += nwaves) {
    unsigned code = wl[e];
    int b = (int)(code >> 10), d = (int)(code & 1023);

    double lg[10], sl[10], ic[10], nt = 0.0;
    #pragma unroll
    for (int s = 0; s < SSEG; s++) { lg[s] = 0.0; sl[s] = 0.0; ic[s] = 0.0; }

    if (haveP) {
      for (int k = lane; k < DIN; k += 64) {     // coalesced WLt rows
        double xv = (double)x[(size_t)b * DIN + k];
        #pragma unroll
        for (int s = 0; s < SSEG; s++)
          lg[s] += xv * (double)WLt[(size_t)(s * 1024 + d) * DIN + k];
      }
    } else {
      for (int k = lane; k < DIN; k += 64) {
        double xv = (double)x[(size_t)b * DIN + k];
        const float* wr = pW + (size_t)k * NPAR + 3 * d;
        #pragma unroll
        for (int s = 0; s < SSEG; s++) {
          lg[s] += xv * (double)wr[s * 3072];
          sl[s] += xv * (double)wr[s * 3072 + 1];
          ic[s] += xv * (double)wr[s * 3072 + 2];
        }
        nt += xv * (double)nW[(size_t)k * DOUT + d];
      }
    }
    #pragma unroll
    for (int off = 32; off > 0; off >>= 1) {
      #pragma unroll
      for (int s = 0; s < SSEG; s++) lg[s] += __shfl_down(lg[s], off);
      if (!haveP) {
        #pragma unroll
        for (int s = 0; s < SSEG; s++) {
          sl[s] += __shfl_down(sl[s], off);
          ic[s] += __shfl_down(ic[s], off);
        }
        nt += __shfl_down(nt, off);
      }
    }

    if (lane == 0) {
      double slope[10], icpt[10], ntv;
      if (haveP) {
        const half_t* Pr = P + (size_t)b * NCOL2;
        #pragma unroll
        for (int s = 0; s < SSEG; s++) {
          slope[s] = tanh((double)(float)Pr[s * 2048 + 2 * d]);
          icpt[s]  = (double)(float)Pr[s * 2048 + 2 * d + 1];
        }
        ntv = (double)(float)Pr[NPK + d];
      } else {
        #pragma unroll
        for (int s = 0; s < SSEG; s++) {
          slope[s] = tanh(sl[s] + (double)pb[s * 3072 + 3 * d + 1]);
          icpt[s]  = ic[s] + (double)pb[s * 3072 + 3 * d + 2];
        }
        ntv = nt + (double)nb[d];
      }
      #pragma unroll
      for (int s = 0; s < SSEG; s++) lg[s] += (double)pb[s * 3072 + 3 * d];

      double mx = -1e300;
      #pragma unroll
      for (int s = 0; s < SSEG; s++) mx = fmax(mx, lg[s]);
      double ew[10], ws = 0.0;
      #pragma unroll
      for (int s = 0; s < SSEG; s++) { ew[s] = exp(lg[s] - mx); ws += ew[s]; }

      double kp[11];
      kp[0] = -1.0;
      double cum = 0.0;
      #pragma unroll
      for (int s = 0; s < SSEG; s++) { cum += ew[s] / ws; kp[s + 1] = cum * 2.0 - 1.0; }

      double tt = (double)t[b];
      double vf[10], resid[10], lm = 0.0, rm = 0.0, integ = 0.0;
      #pragma unroll
      for (int s = 0; s < SSEG; s++) {
        double st = kp[s], en = kp[s + 1];
        bool v = ((tt >= st) && (tt < en)) || ((tt == 1.0) && (en == 1.0));
        double vv = v ? 1.0 : 0.0;
        vf[s] = vv;
        resid[s] = slope[s] * tt + icpt[s];
        lm += (tt - st) * vv;
        rm += (en - tt) * vv;
        integ += 0.5 * slope[s] * (en * en - st * st) + icpt[s] * (ew[s] / ws);
      }
      double rLV = 0.0, rV = 0.0, rRV = 0.0;
      #pragma unroll
      for (int s = 0; s < SSEG; s++) {
        double lv = (s == 0) ? vf[0] : vf[s - 1];
        double rv = (s == 9) ? vf[9] : vf[s + 1];
        rLV += resid[s] * lv;
        rV  += resid[s] * vf[s];
        rRV += resid[s] * rv;
      }
      double lw = 1.0 / (1.0 + exp(50.0 * lm));
      double rw = 1.0 / (1.0 + exp(50.0 * rm));
      double res = lw * rLV + (1.0 - lw - rw) * rV + rw * rRV - 0.5 * integ + ntv;
      out[(size_t)b * DOUT + d] = (float)res;
    }
  }
}

// ---------------------------------------------------------------------------
extern "C" void kernel_launch(void* const* d_in, const int* in_sizes, int n_in,
                              void* d_out, int out_size, void* d_ws, size_t ws_size,
                              hipStream_t stream) {
  const float* x  = (const float*)d_in[0];
  const float* t  = (const float*)d_in[1];
  const float* pW = (const float*)d_in[2];
  const float* pb = (const float*)d_in[3];
  const float* nW = (const float*)d_in[4];
  const float* nb = (const float*)d_in[5];
  float* out = (float*)d_out;

  // workspace layout (counter+worklist first so the fallback works with tiny ws)
  const size_t o_cnt = 0;
  const size_t o_wl  = 64;
  const size_t o_xh  = o_wl  + (size_t)WL_CAP * 4;         //  4 MiB
  const size_t o_xl  = o_xh  + (size_t)BS * DIN * 2;       //  4 MiB
  const size_t o_wsm = o_xl  + (size_t)BS * DIN * 2;       // 44 MiB (NCOL2 fp16)
  const size_t o_wh  = o_wsm + (size_t)NCOL2 * DIN * 2;    // 20 MiB
  const size_t o_wlo = o_wh  + (size_t)NLG * DIN * 2;      // 20 MiB
  const size_t o_wlt = o_wlo + (size_t)NLG * DIN * 2;      // 40 MiB (fp32 logit W^T)
  const size_t o_p   = o_wlt + (size_t)NLG * DIN * 4;      // 88 MiB (fp16 P2)
  const size_t o_lg  = o_p   + (size_t)BS * NCOL2 * 2;     // 84 MiB
  const size_t need  = o_lg  + (size_t)BS * NLG * 4;       // ~308 MiB total

  bool have_wl = ws_size >= 1024 * 1024;
  unsigned* cnt = (unsigned*)((char*)d_ws + o_cnt);
  unsigned* wl  = (unsigned*)((char*)d_ws + o_wl);
  unsigned cap  = 0;
  if (have_wl) {
    size_t avail = (ws_size >= need) ? (size_t)WL_CAP
                                     : (ws_size - o_wl) / 4;
    cap = (unsigned)(avail < WL_CAP ? avail : WL_CAP);
  }

  if (ws_size >= need) {
    half_t* xh  = (half_t*)((char*)d_ws + o_xh);
    half_t* xl  = (half_t*)((char*)d_ws + o_xl);
    half_t* wsm = (half_t*)((char*)d_ws + o_wsm);
    half_t* wh  = (half_t*)((char*)d_ws + o_wh);
    half_t* wlo = (half_t*)((char*)d_ws + o_wlo);
    float*  wlt = (float*)((char*)d_ws + o_wlt);
    half_t* P   = (half_t*)((char*)d_ws + o_p);
    float*  Lg  = (float*)((char*)d_ws + o_lg);

    k_prep<<<NB_SPLIT + NB_NORM + NB_TRW, 256, 0, stream>>>(x, xh, xl, nW, pW,
                                                            wsm, wh, wlo, wlt, cnt);
    k_gemm2<<<GEMM_BLKS, 512, 0, stream>>>(xh, xl, wh, wlo, wsm, Lg, P, pb, nb);
    k_pointwise<<<dim3(BS, DOUT / 256), 256, 0, stream>>>(P, Lg, t, out, cnt,
                                                          have_wl ? wl : nullptr, cap);
    if (have_wl)
      k_redo<<<256, 256, 0, stream>>>(x, t, pW, pb, nW, nb, P, wlt, 1, cnt, wl, cap, out);
  } else {
    if (have_wl) k_zero<<<1, 64, 0, stream>>>(cnt);
    k_naive<<<dim3(BS, DOUT / 256), 256, 0, stream>>>(x, t, pW, pb, nW, nb, out, cnt,
                                                      have_wl ? wl : nullptr, cap);
    if (have_wl)
      k_redo<<<256, 256, 0, stream>>>(x, t, pW, pb, nW, nb, nullptr, nullptr, 0,
                                      cnt, wl, cap, out);
  }
}

// Round 4
// 556.411 us; speedup vs baseline: 1.0167x; 1.0167x over previous
//
#include <hip/hip_runtime.h>
#include <cstdint>
#include <cstddef>

// Problem constants (fixed by the reference setup)
#define BS    2048
#define DIN   1024
#define DOUT  1024
#define SSEG  10
#define NPAR  30720          // dout * S * 3
#define NPK   20480          // packed smooth cols: S*DOUT*2 (ch1,ch2)
#define NCOL2 21504          // NPK + DOUT (norm appended)
#define NLG   10240          // S * DOUT logit columns (channel 0)
#define TAU   5e-5f          // near-boundary radius (~10x worst fp32-pipeline kp error)
#define WL_CAP 1048576u      // worklist capacity (entries)

// prep kernel regions
#define NB_SPLIT 2048        // x fp16x2 split blocks
#define NB_NORM  1024        // norm_W transpose blocks
#define NB_TRW   2560        // param_W transpose blocks (80 x 32)

// unified GEMM grid: 320 logit blocks + 672 smooth blocks, 256x256 tiles.
#define GEMM_BLKS 992

typedef _Float16 half_t;
typedef __attribute__((ext_vector_type(8))) _Float16 half8;
typedef __attribute__((ext_vector_type(4))) _Float16 half4;
typedef __attribute__((ext_vector_type(2))) _Float16 half2v;
typedef __attribute__((ext_vector_type(4))) float   floatx4;

__device__ __forceinline__ void gload16(const void* g, void* l) {
  __builtin_amdgcn_global_load_lds(
      (const __attribute__((address_space(1))) void*)g,
      (__attribute__((address_space(3))) void*)l, 16, 0, 0);
}

// ---------------------------------------------------------------------------
__global__ void k_zero(unsigned* c) { if (threadIdx.x == 0) *c = 0; }

// ---------------------------------------------------------------------------
// Prep (3 regions):
//  [0, 2048):        x -> xh/xl fp16x2 split (+ zero worklist counter)
//  [2048, 3072):     norm_W transpose -> wsm rows [NPK, NCOL2)
//  [3072, 5632):     param_W 32k x 384col tiles ->
//                      wsm (ch1/ch2 fp16), wh/wlo (fp16x2 of 32w), wlt (fp32)
// ---------------------------------------------------------------------------
__global__ __launch_bounds__(256) void k_prep(const float* __restrict__ x,
                                              half_t* __restrict__ xh,
                                              half_t* __restrict__ xl,
                                              const float* __restrict__ nW,
                                              const float* __restrict__ pW,
                                              half_t* __restrict__ wsm,
                                              half_t* __restrict__ wh,
                                              half_t* __restrict__ wlo,
                                              float* __restrict__ wlt,
                                              unsigned* __restrict__ cnt) {
  __shared__ float tile[32][384];              // 48 KB (transw region)
  int bid = blockIdx.x;
  int tid = threadIdx.x;

  if (bid < NB_SPLIT) {
    if (bid == 0 && tid == 0) *cnt = 0;
    int i = bid * 256 + tid;                   // float4 groups over BS*DIN
    floatx4 v = ((const floatx4*)x)[i];
    half4 h, l;
    #pragma unroll
    for (int c = 0; c < 4; c++) { h[c] = (half_t)v[c]; l[c] = (half_t)(v[c] - (float)h[c]); }
    ((half4*)xh)[i] = h;
    ((half4*)xl)[i] = l;
    return;
  }

  if (bid < NB_SPLIT + NB_NORM) {
    int b2 = bid - NB_SPLIT;                   // 0..1023
    int col0 = (b2 & 31) * 32;
    int k0   = (b2 >> 5) * 32;
    int tx = tid & 31;
    int ty = tid >> 5;
    float* t33 = &tile[0][0];                  // reuse LDS as 32x33
    #pragma unroll
    for (int r = ty; r < 32; r += 8)
      t33[r * 33 + tx] = nW[(size_t)(k0 + r) * DOUT + col0 + tx];
    __syncthreads();
    #pragma unroll
    for (int r = ty; r < 32; r += 8)
      wsm[(size_t)(col0 + r + NPK) * DIN + k0 + tx] = (half_t)t33[tx * 33 + r];
    return;
  }

  // ---- transw region ----
  int b3 = bid - NB_SPLIT - NB_NORM;           // 0..2559
  int bx = b3 % 80;                            // 384-col group
  int k0 = (b3 / 80) * 32;                     // k tile
  int s  = bx >> 3;                            // logit segment
  int d0 = (bx & 7) * 128;

  const float* sb = pW + (size_t)k0 * NPAR + bx * 384;
  for (int i = tid; i < 32 * 96; i += 256) {   // 12 coalesced float4/thread
    int r = i / 96, q = i - r * 96;
    ((floatx4*)&tile[r][0])[q] = ((const floatx4*)(sb + (size_t)r * NPAR))[q];
  }
  __syncthreads();

  for (int ci = tid; ci < 3072; ci += 256) {
    if (ci < 1024) {                           // wsm ch1/ch2: 256 rows x 4 chunks
      int rl = ci >> 2, kc = ci & 3;
      int jj = rl >> 1, cbit = rl & 1;
      int col = 3 * jj + 1 + cbit;
      half8 v;
      #pragma unroll
      for (int m = 0; m < 8; m++) v[m] = (half_t)tile[kc * 8 + m][col];
      *(half8*)(wsm + (size_t)(s * 2048 + 2 * (d0 + jj) + cbit) * DIN + k0 + kc * 8) = v;
    } else if (ci < 1536) {                    // wh: 128 rows x 4 chunks
      int u = ci - 1024;
      int jj = u >> 2, kc = u & 3;
      half8 v;
      #pragma unroll
      for (int m = 0; m < 8; m++) v[m] = (half_t)(tile[kc * 8 + m][3 * jj] * 32.0f);
      *(half8*)(wh + (size_t)(s * 1024 + d0 + jj) * DIN + k0 + kc * 8) = v;
    } else if (ci < 2048) {                    // wlo: 128 rows x 4 chunks
      int u = ci - 1536;
      int jj = u >> 2, kc = u & 3;
      half8 v;
      #pragma unroll
      for (int m = 0; m < 8; m++) {
        float raw = tile[kc * 8 + m][3 * jj] * 32.0f;   // exact pow2 scale
        half_t h = (half_t)raw;
        v[m] = (half_t)(raw - (float)h);
      }
      *(half8*)(wlo + (size_t)(s * 1024 + d0 + jj) * DIN + k0 + kc * 8) = v;
    } else {                                   // wlt fp32: 128 rows x 8 chunks
      int u = ci - 2048;
      int jj = u >> 3, kc = u & 7;
      floatx4 v;
      #pragma unroll
      for (int m = 0; m < 4; m++) v[m] = tile[kc * 4 + m][3 * jj];
      *(floatx4*)(wlt + (size_t)(s * 1024 + d0 + jj) * DIN + k0 + kc * 4) = v;
    }
  }
}

// ---------------------------------------------------------------------------
// Unified GEMM, 256x256 tile, 512 threads (8 waves 2x4), per-wave 128x64 out.
//
// Phase-split schedule (m201 template): each phase = {ds_read frags;
// issue part of next-chunk staging; s_barrier; lgkmcnt(0)+sched_barrier(0);
// setprio(1); MFMA cluster; setprio(0); s_barrier}. Counted vmcnt only at
// chunk boundaries.
//
// mode 0 (bid<320, logit): per 32-k chunk stage {xh,xl,wh,wlo} (4x16KB) once,
//   3 product phases (xh*wh / xl*wh / xh*wlo) of 32 MFMA each. LDS: 2x64KB
//   chunk-set dbuf; the 8 stage loads split across phases 1-2, so the
//   chunk-end vmcnt(0) waits on ~2-phase-old loads (~free).
// mode 1 (bid>=320, smooth): P = xh*wsm^T; 4-deep {A,B} ring (4x32KB),
//   stage 3 tiles ahead, 2 phases of 16 MFMA, steady-state vmcnt(8).
//
// XCD locality: mt = bid&7 -> each XCD reads ONE 256-row xh/xl panel.
//
// LDS tile layout (16KB): 128 lines x 128B; line L = rows {2L,2L+1} x 32 k.
// 16B slot s of line L holds global chunk s^(L&7) (XOR swizzle on both the
// gload source address and the ds_read address -> conflict-free, measured 0).
// ---------------------------------------------------------------------------
__global__ __launch_bounds__(512, 2) void k_gemm2(
    const half_t* __restrict__ xh, const half_t* __restrict__ xl,
    const half_t* __restrict__ wh, const half_t* __restrict__ wlo,
    const half_t* __restrict__ wsm,
    float* __restrict__ Lg, half_t* __restrict__ P,
    const float* __restrict__ pb, const float* __restrict__ nb) {
  __shared__ __attribute__((aligned(128))) char lds[131072];

  int bid = blockIdx.x;
  int tid = threadIdx.x;
  int w = tid >> 6, l = tid & 63;
  int wr = w >> 2, wc = w & 3;                 // wave grid 2 (rows) x 4 (cols)
  int l15 = l & 15, quad = l >> 4;

  int mode, mt, nt;
  if (bid < 320) { mode = 0; mt = bid & 7; nt = bid >> 3; }   // 8 x 40
  else { int s2 = bid - 320; mode = 1; mt = s2 & 7; nt = s2 >> 3; } // 8 x 84
  int m0 = mt * 256, n0 = nt * 256;

  // staging geometry: lane l covers line (l>>3), linear slot (l&7); source
  // chunk pre-swizzled: s' = (l&7)^(l>>3)  (rule: swizzle both sides).
  int sp = (l & 7) ^ ((l >> 3) & 7);
  int srowA = m0 + w * 32 + 2 * (l >> 3) + (sp >> 2);
  int srowB = n0 + w * 32 + 2 * (l >> 3) + (sp >> 2);
  int scol = (sp & 3) * 8;

  // fragment read: row base+l15 -> line (l15>>1), half l15&1, chunk quad;
  // swizzled slot = (((l15&1)<<2)|quad) ^ (l15>>1).
  int lofs = (l15 >> 1) * 128 + (((((l15 & 1) << 2) | quad) ^ (l15 >> 1)) << 4);

  floatx4 acc[8][4] = {};

  if (mode == 0) {
    // ---- logit: 32 chunks, dbuf of 64KB chunk-sets, 3 phases/chunk ----
    const half_t* gA = xh + (size_t)srowA * DIN + scol;
    const half_t* gX = xl + (size_t)srowA * DIN + scol;
    const half_t* gH = wh + (size_t)srowB * DIN + scol;
    const half_t* gL = wlo + (size_t)srowB * DIN + scol;

    {   // prologue: full chunk 0
      char* base = lds + w * 2048;
      gload16(gA, base);                gload16(gA + 16 * DIN, base + 1024);
      gload16(gX, base + 16384);        gload16(gX + 16 * DIN, base + 16384 + 1024);
      gload16(gH, base + 32768);        gload16(gH + 16 * DIN, base + 32768 + 1024);
      gload16(gL, base + 49152);        gload16(gL + 16 * DIN, base + 49152 + 1024);
    }
    asm volatile("s_waitcnt vmcnt(0)" ::: "memory");
    __builtin_amdgcn_s_barrier();

    for (int c = 0; c < 32; ++c) {
      const char* base = lds + (c & 1) * 65536;
      const char* aXH = base + wr * 8192 + lofs;
      const char* aXL = base + 16384 + wr * 8192 + lofs;
      const char* bWH = base + 32768 + wc * 4096 + lofs;
      const char* bWL = base + 49152 + wc * 4096 + lofs;
      bool pre = (c + 1 < 32);
      char* sbase = lds + ((c + 1) & 1) * 65536 + w * 2048;
      int ko = (c + 1) * 32;

      // ---- phase 1: bh + a0/a1 reads; stage xh/xl of c+1; 32 MFMA ----
      half8 bh[4], a0[4], a1[4];
      #pragma unroll
      for (int ni = 0; ni < 4; ni++) bh[ni] = *(const half8*)(bWH + ni * 1024);
      #pragma unroll
      for (int mi = 0; mi < 4; mi++) a0[mi] = *(const half8*)(aXH + mi * 1024);
      #pragma unroll
      for (int mi = 0; mi < 4; mi++) a1[mi] = *(const half8*)(aXH + 4096 + mi * 1024);
      if (pre) {
        gload16(gA + ko, sbase);           gload16(gA + ko + 16 * DIN, sbase + 1024);
        gload16(gX + ko, sbase + 16384);   gload16(gX + ko + 16 * DIN, sbase + 16384 + 1024);
      }
      __builtin_amdgcn_s_barrier();
      asm volatile("s_waitcnt lgkmcnt(0)" ::: "memory");
      __builtin_amdgcn_sched_barrier(0);
      __builtin_amdgcn_s_setprio(1);
      #pragma unroll
      for (int mi = 0; mi < 4; mi++)
        #pragma unroll
        for (int ni = 0; ni < 4; ni++) {
          acc[mi][ni]     = __builtin_amdgcn_mfma_f32_16x16x32_f16(a0[mi], bh[ni], acc[mi][ni], 0, 0, 0);
          acc[4 + mi][ni] = __builtin_amdgcn_mfma_f32_16x16x32_f16(a1[mi], bh[ni], acc[4 + mi][ni], 0, 0, 0);
        }
      __builtin_amdgcn_s_setprio(0);
      __builtin_amdgcn_s_barrier();

      // ---- phase 2: x0/x1 reads; stage wh/wlo of c+1; 32 MFMA ----
      half8 x0[4], x1[4];
      #pragma unroll
      for (int mi = 0; mi < 4; mi++) x0[mi] = *(const half8*)(aXL + mi * 1024);
      #pragma unroll
      for (int mi = 0; mi < 4; mi++) x1[mi] = *(const half8*)(aXL + 4096 + mi * 1024);
      if (pre) {
        gload16(gH + ko, sbase + 32768);   gload16(gH + ko + 16 * DIN, sbase + 32768 + 1024);
        gload16(gL + ko, sbase + 49152);   gload16(gL + ko + 16 * DIN, sbase + 49152 + 1024);
      }
      __builtin_amdgcn_s_barrier();
      asm volatile("s_waitcnt lgkmcnt(0)" ::: "memory");
      __builtin_amdgcn_sched_barrier(0);
      __builtin_amdgcn_s_setprio(1);
      #pragma unroll
      for (int mi = 0; mi < 4; mi++)
        #pragma unroll
        for (int ni = 0; ni < 4; ni++) {
          acc[mi][ni]     = __builtin_amdgcn_mfma_f32_16x16x32_f16(x0[mi], bh[ni], acc[mi][ni], 0, 0, 0);
          acc[4 + mi][ni] = __builtin_amdgcn_mfma_f32_16x16x32_f16(x1[mi], bh[ni], acc[4 + mi][ni], 0, 0, 0);
        }
      __builtin_amdgcn_s_setprio(0);
      __builtin_amdgcn_s_barrier();

      // ---- phase 3: bl reads; 32 MFMA; chunk-end counted wait ----
      half8 bl[4];
      #pragma unroll
      for (int ni = 0; ni < 4; ni++) bl[ni] = *(const half8*)(bWL + ni * 1024);
      __builtin_amdgcn_s_barrier();
      asm volatile("s_waitcnt lgkmcnt(0)" ::: "memory");
      __builtin_amdgcn_sched_barrier(0);
      __builtin_amdgcn_s_setprio(1);
      #pragma unroll
      for (int mi = 0; mi < 4; mi++)
        #pragma unroll
        for (int ni = 0; ni < 4; ni++) {
          acc[mi][ni]     = __builtin_amdgcn_mfma_f32_16x16x32_f16(a0[mi], bl[ni], acc[mi][ni], 0, 0, 0);
          acc[4 + mi][ni] = __builtin_amdgcn_mfma_f32_16x16x32_f16(a1[mi], bl[ni], acc[4 + mi][ni], 0, 0, 0);
        }
      __builtin_amdgcn_s_setprio(0);
      if (pre) {
        __builtin_amdgcn_sched_barrier(0);
        asm volatile("s_waitcnt vmcnt(0)" ::: "memory");
        __builtin_amdgcn_s_barrier();
      }
    }
  } else {
    // ---- smooth: 32 kts, 4-deep {A,B} ring, 2 phases/kt, counted vmcnt ----
    const half_t* gA = xh + (size_t)srowA * DIN + scol;
    const half_t* gB = wsm + (size_t)srowB * DIN + scol;
    auto stage1 = [&](int kt) {                // 4 gload16 per wave
      char* base = lds + ((kt & 3) * 32768) + w * 2048;
      gload16(gA + kt * 32, base);            gload16(gA + kt * 32 + 16 * DIN, base + 1024);
      gload16(gB + kt * 32, base + 16384);    gload16(gB + kt * 32 + 16 * DIN, base + 16384 + 1024);
    };

    stage1(0); stage1(1); stage1(2);
    asm volatile("s_waitcnt vmcnt(8)" ::: "memory");
    __builtin_amdgcn_s_barrier();

    for (int kt = 0; kt < 32; ++kt) {
      const char* base = lds + (kt & 3) * 32768;
      const char* a = base + wr * 8192 + lofs;
      const char* b = base + 16384 + wc * 4096 + lofs;

      // ---- phase 1: bf + af reads; stage kt+3; 16 MFMA ----
      half8 bf[4], af[4];
      #pragma unroll
      for (int ni = 0; ni < 4; ni++) bf[ni] = *(const half8*)(b + ni * 1024);
      #pragma unroll
      for (int mi = 0; mi < 4; mi++) af[mi] = *(const half8*)(a + mi * 1024);
      if (kt + 3 < 32) stage1(kt + 3);
      __builtin_amdgcn_s_barrier();
      asm volatile("s_waitcnt lgkmcnt(0)" ::: "memory");
      __builtin_amdgcn_sched_barrier(0);
      __builtin_amdgcn_s_setprio(1);
      #pragma unroll
      for (int mi = 0; mi < 4; mi++)
        #pragma unroll
        for (int ni = 0; ni < 4; ni++)
          acc[mi][ni] = __builtin_amdgcn_mfma_f32_16x16x32_f16(af[mi], bf[ni], acc[mi][ni], 0, 0, 0);
      __builtin_amdgcn_s_setprio(0);
      __builtin_amdgcn_s_barrier();

      // ---- phase 2: ag reads; 16 MFMA; kt-end counted wait ----
      half8 ag[4];
      #pragma unroll
      for (int mi = 0; mi < 4; mi++) ag[mi] = *(const half8*)(a + 4096 + mi * 1024);
      __builtin_amdgcn_s_barrier();
      asm volatile("s_waitcnt lgkmcnt(0)" ::: "memory");
      __builtin_amdgcn_sched_barrier(0);
      __builtin_amdgcn_s_setprio(1);
      #pragma unroll
      for (int mi = 0; mi < 4; mi++)
        #pragma unroll
        for (int ni = 0; ni < 4; ni++)
          acc[4 + mi][ni] = __builtin_amdgcn_mfma_f32_16x16x32_f16(ag[mi], bf[ni], acc[4 + mi][ni], 0, 0, 0);
      __builtin_amdgcn_s_setprio(0);
      if (kt < 29) {
        __builtin_amdgcn_sched_barrier(0);
        asm volatile("s_waitcnt vmcnt(8)" ::: "memory");
        __builtin_amdgcn_s_barrier();
      } else if (kt == 29) {
        __builtin_amdgcn_sched_barrier(0);
        asm volatile("s_waitcnt vmcnt(4)" ::: "memory");
        __builtin_amdgcn_s_barrier();
      } else if (kt == 30) {
        __builtin_amdgcn_sched_barrier(0);
        asm volatile("s_waitcnt vmcnt(0)" ::: "memory");
        __builtin_amdgcn_s_barrier();
      }
    }
  }

  // ---- epilogue ----
  int rbase = m0 + wr * 128 + quad * 4;
  int cbase = n0 + wc * 64 + l15;
  if (mode == 0) {
    #pragma unroll
    for (int ni = 0; ni < 4; ni++) {
      int col = cbase + ni * 16;               // packed s*1024+d
      float bias = pb[(col >> 10) * 3072 + (col & 1023) * 3];
      #pragma unroll
      for (int mi = 0; mi < 8; mi++) {
        int row = rbase + mi * 16;
        floatx4 v = acc[mi][ni];
        #pragma unroll
        for (int r = 0; r < 4; r++)
          Lg[(size_t)(row + r) * NLG + col] = v[r] * 0.03125f + bias;
      }
    }
  } else {
    #pragma unroll
    for (int ni = 0; ni < 4; ni++) {
      int col = cbase + ni * 16;
      float bias;
      if (col < NPK) {
        int s = col >> 11, rem = col & 2047;
        bias = pb[s * 3072 + 3 * (rem >> 1) + 1 + (rem & 1)];
      } else {
        bias = nb[col - NPK];
      }
      #pragma unroll
      for (int mi = 0; mi < 8; mi++) {
        int row = rbase + mi * 16;
        floatx4 v = acc[mi][ni];
        #pragma unroll
        for (int r = 0; r < 4; r++)
          P[(size_t)(row + r) * NCOL2 + col] = (half_t)(v[r] + bias);
      }
    }
  }
}

// ---------------------------------------------------------------------------
// fp32 formula; mind = min_j |t - kp[j]| for near-boundary flagging
// ---------------------------------------------------------------------------
__device__ __forceinline__ float spiking_eval(const float* p, float tt, float* mind) {
  float mx = -1e30f;
  #pragma unroll
  for (int s = 0; s < SSEG; s++) mx = fmaxf(mx, p[3 * s]);
  float ew[10], wsum = 0.0f;
  #pragma unroll
  for (int s = 0; s < SSEG; s++) { ew[s] = __expf(p[3 * s] - mx); wsum += ew[s]; }
  float inv = 1.0f / wsum;

  float kp[11];
  kp[0] = -1.0f;
  float cum = 0.0f, md = 1e30f;
  #pragma unroll
  for (int s = 0; s < SSEG; s++) {
    cum += ew[s] * inv;
    kp[s + 1] = cum * 2.0f - 1.0f;
    md = fminf(md, fabsf(tt - kp[s + 1]));
  }
  *mind = md;

  float vf[10], resid[10];
  float lm = 0.0f, rm = 0.0f, integ = 0.0f;
  #pragma unroll
  for (int s = 0; s < SSEG; s++) {
    float p1 = p[3 * s + 1], p2 = p[3 * s + 2];
    float e2 = __expf(2.0f * fabsf(p1));
    float th = copysignf(1.0f - 2.0f / (e2 + 1.0f), p1);
    resid[s] = th * tt + p2;
    float st = kp[s], en = kp[s + 1];
    bool v = ((tt >= st) && (tt < en)) || ((tt == 1.0f) && (en == 1.0f));
    float vv = v ? 1.0f : 0.0f;
    vf[s] = vv;
    lm += (tt - st) * vv;
    rm += (en - tt) * vv;
    integ += 0.5f * th * (en * en - st * st) + p2 * (ew[s] * inv);
  }
  float resLV = 0.0f, resV = 0.0f, resRV = 0.0f;
  #pragma unroll
  for (int s = 0; s < SSEG; s++) {
    float lv = (s == 0) ? vf[0] : vf[s - 1];
    float rv = (s == 9) ? vf[9] : vf[s + 1];
    resLV += resid[s] * lv;
    resV  += resid[s] * vf[s];
    resRV += resid[s] * rv;
  }
  float lw = 1.0f / (1.0f + __expf(50.0f * lm));
  float rw = 1.0f / (1.0f + __expf(50.0f * rm));
  float swt = 1.0f - lw - rw;
  return lw * resLV + swt * resV + rw * resRV - 0.5f * integ + p[30];
}

// ---------------------------------------------------------------------------
// Pointwise: logits fp32 from Lg, ch1/2+norm fp16 from P. Flags near-boundary.
// ---------------------------------------------------------------------------
__global__ __launch_bounds__(256) void k_pointwise(const half_t* __restrict__ P,
                                                   const float* __restrict__ Lg,
                                                   const float* __restrict__ t,
                                                   float* __restrict__ out,
                                                   unsigned* __restrict__ cnt,
                                                   unsigned* __restrict__ wl,
                                                   unsigned cap) {
  __shared__ __attribute__((aligned(16))) half_t sp[SSEG * 512];
  int b = blockIdx.x, dg = blockIdx.y, tid = threadIdx.x;
  const half_t* Pb = P + (size_t)b * NCOL2;
  for (int i = tid; i < SSEG * 64; i += 256) {     // 640 x 16B
    int s = i >> 6, e = i & 63;
    ((uint4*)sp)[(s << 6) + e] = ((const uint4*)(Pb + s * 2048 + dg * 512))[e];
  }
  float tt = t[b];
  float nt = (float)Pb[NPK + dg * 256 + tid];
  const float* Lb = Lg + (size_t)b * NLG + dg * 256 + tid;
  __syncthreads();

  float p[31];
  #pragma unroll
  for (int s = 0; s < SSEG; s++) {
    p[3 * s] = Lb[s * 1024];                       // accurate logit (bias incl.)
    half2v hv = ((const half2v*)sp)[s * 256 + tid];  // 4B/lane, conflict-free
    p[3 * s + 1] = (float)hv.x;
    p[3 * s + 2] = (float)hv.y;
  }
  p[30] = nt;
  float mind;
  float r = spiking_eval(p, tt, &mind);
  int d = dg * 256 + tid;
  out[(size_t)b * DOUT + d] = r;
  if (wl != nullptr && mind < TAU) {
    unsigned idx = atomicAdd(cnt, 1u);
    if (idx < cap) wl[idx] = ((unsigned)b << 10) | (unsigned)d;
  }
}

// ---------------------------------------------------------------------------
// Fallback: fused naive fp32 + flagging (tiny-workspace insurance)
// ---------------------------------------------------------------------------
__global__ __launch_bounds__(256) void k_naive(const float* __restrict__ x,
                                               const float* __restrict__ t,
                                               const float* __restrict__ pW,
                                               const float* __restrict__ pb,
                                               const float* __restrict__ nW,
                                               const float* __restrict__ nb,
                                               float* __restrict__ out,
                                               unsigned* __restrict__ cnt,
                                               unsigned* __restrict__ wl,
                                               unsigned cap) {
  __shared__ float xs[DIN];
  int b = blockIdx.x, dg = blockIdx.y, tid = threadIdx.x;
  for (int i = tid; i < DIN; i += 256) xs[i] = x[(size_t)b * DIN + i];
  __syncthreads();
  int d = dg * 256 + tid;
  float acc[31];
  #pragma unroll
  for (int i = 0; i < 31; i++) acc[i] = 0.0f;
  for (int k = 0; k < DIN; k++) {
    float xv = xs[k];
    const float* wr = pW + (size_t)k * NPAR + 3 * d;
    #pragma unroll
    for (int s = 0; s < SSEG; s++) {
      acc[3 * s]     += xv * wr[s * 3072];
      acc[3 * s + 1] += xv * wr[s * 3072 + 1];
      acc[3 * s + 2] += xv * wr[s * 3072 + 2];
    }
    acc[30] += xv * nW[(size_t)k * DOUT + d];
  }
  #pragma unroll
  for (int s = 0; s < SSEG; s++) {
    acc[3 * s]     += pb[s * 3072 + 3 * d];
    acc[3 * s + 1] += pb[s * 3072 + 3 * d + 1];
    acc[3 * s + 2] += pb[s * 3072 + 3 * d + 2];
  }
  acc[30] += nb[d];
  float mind;
  float r = spiking_eval(acc, t[b], &mind);
  out[(size_t)b * DOUT + d] = r;
  if (wl != nullptr && mind < TAU) {
    unsigned idx = atomicAdd(cnt, 1u);
    if (idx < cap) wl[idx] = ((unsigned)b << 10) | (unsigned)d;
  }
}

// ---------------------------------------------------------------------------
// f64 redo: one wave per flagged (b,d). haveP: coalesced WLt logit weights +
// fp16 smooth channels from P. !haveP: pW gather (fallback path).
// ---------------------------------------------------------------------------
__global__ __launch_bounds__(256) void k_redo(const float* __restrict__ x,
                                              const float* __restrict__ t,
                                              const float* __restrict__ pW,
                                              const float* __restrict__ pb,
                                              const float* __restrict__ nW,
                                              const float* __restrict__ nb,
                                              const half_t* __restrict__ P,
                                              const float* __restrict__ WLt,
                                              int haveP,
                                              const unsigned* __restrict__ cnt,
                                              const unsigned* __restrict__ wl,
                                              unsigned cap,
                                              float* __restrict__ out) {
  unsigned n = *cnt;
  if (n > cap) n = cap;
  int lane = threadIdx.x & 63;
  unsigned wave = (blockIdx.x * 256 + threadIdx.x) >> 6;
  unsigned nwaves = (gridDim.x * 256) >> 6;

  for (unsigned e = wave; e < n; e += nwaves) {
    unsigned code = wl[e];
    int b = (int)(code >> 10), d = (int)(code & 1023);

    double lg[10], sl[10], ic[10], nt = 0.0;
    #pragma unroll
    for (int s = 0; s < SSEG; s++) { lg[s] = 0.0; sl[s] = 0.0; ic[s] = 0.0; }

    if (haveP) {
      for (int k = lane; k < DIN; k += 64) {     // coalesced WLt rows
        double xv = (double)x[(size_t)b * DIN + k];
        #pragma unroll
        for (int s = 0; s < SSEG; s++)
          lg[s] += xv * (double)WLt[(size_t)(s * 1024 + d) * DIN + k];
      }
    } else {
      for (int k = lane; k < DIN; k += 64) {
        double xv = (double)x[(size_t)b * DIN + k];
        const float* wr = pW + (size_t)k * NPAR + 3 * d;
        #pragma unroll
        for (int s = 0; s < SSEG; s++) {
          lg[s] += xv * (double)wr[s * 3072];
          sl[s] += xv * (double)wr[s * 3072 + 1];
          ic[s] += xv * (double)wr[s * 3072 + 2];
        }
        nt += xv * (double)nW[(size_t)k * DOUT + d];
      }
    }
    #pragma unroll
    for (int off = 32; off > 0; off >>= 1) {
      #pragma unroll
      for (int s = 0; s < SSEG; s++) lg[s] += __shfl_down(lg[s], off);
      if (!haveP) {
        #pragma unroll
        for (int s = 0; s < SSEG; s++) {
          sl[s] += __shfl_down(sl[s], off);
          ic[s] += __shfl_down(ic[s], off);
        }
        nt += __shfl_down(nt, off);
      }
    }

    if (lane == 0) {
      double slope[10], icpt[10], ntv;
      if (haveP) {
        const half_t* Pr = P + (size_t)b * NCOL2;
        #pragma unroll
        for (int s = 0; s < SSEG; s++) {
          slope[s] = tanh((double)(float)Pr[s * 2048 + 2 * d]);
          icpt[s]  = (double)(float)Pr[s * 2048 + 2 * d + 1];
        }
        ntv = (double)(float)Pr[NPK + d];
      } else {
        #pragma unroll
        for (int s = 0; s < SSEG; s++) {
          slope[s] = tanh(sl[s] + (double)pb[s * 3072 + 3 * d + 1]);
          icpt[s]  = ic[s] + (double)pb[s * 3072 + 3 * d + 2];
        }
        ntv = nt + (double)nb[d];
      }
      #pragma unroll
      for (int s = 0; s < SSEG; s++) lg[s] += (double)pb[s * 3072 + 3 * d];

      double mx = -1e300;
      #pragma unroll
      for (int s = 0; s < SSEG; s++) mx = fmax(mx, lg[s]);
      double ew[10], ws = 0.0;
      #pragma unroll
      for (int s = 0; s < SSEG; s++) { ew[s] = exp(lg[s] - mx); ws += ew[s]; }

      double kp[11];
      kp[0] = -1.0;
      double cum = 0.0;
      #pragma unroll
      for (int s = 0; s < SSEG; s++) { cum += ew[s] / ws; kp[s + 1] = cum * 2.0 - 1.0; }

      double tt = (double)t[b];
      double vf[10], resid[10], lm = 0.0, rm = 0.0, integ = 0.0;
      #pragma unroll
      for (int s = 0; s < SSEG; s++) {
        double st = kp[s], en = kp[s + 1];
        bool v = ((tt >= st) && (tt < en)) || ((tt == 1.0) && (en == 1.0));
        double vv = v ? 1.0 : 0.0;
        vf[s] = vv;
        resid[s] = slope[s] * tt + icpt[s];
        lm += (tt - st) * vv;
        rm += (en - tt) * vv;
        integ += 0.5 * slope[s] * (en * en - st * st) + icpt[s] * (ew[s] / ws);
      }
      double rLV = 0.0, rV = 0.0, rRV = 0.0;
      #pragma unroll
      for (int s = 0; s < SSEG; s++) {
        double lv = (s == 0) ? vf[0] : vf[s - 1];
        double rv = (s == 9) ? vf[9] : vf[s + 1];
        rLV += resid[s] * lv;
        rV  += resid[s] * vf[s];
        rRV += resid[s] * rv;
      }
      double lw = 1.0 / (1.0 + exp(50.0 * lm));
      double rw = 1.0 / (1.0 + exp(50.0 * rm));
      double res = lw * rLV + (1.0 - lw - rw) * rV + rw * rRV - 0.5 * integ + ntv;
      out[(size_t)b * DOUT + d] = (float)res;
    }
  }
}

// ---------------------------------------------------------------------------
extern "C" void kernel_launch(void* const* d_in, const int* in_sizes, int n_in,
                              void* d_out, int out_size, void* d_ws, size_t ws_size,
                              hipStream_t stream) {
  const float* x  = (const float*)d_in[0];
  const float* t  = (const float*)d_in[1];
  const float* pW = (const float*)d_in[2];
  const float* pb = (const float*)d_in[3];
  const float* nW = (const float*)d_in[4];
  const float* nb = (const float*)d_in[5];
  float* out = (float*)d_out;

  // workspace layout (counter+worklist first so the fallback works with tiny ws)
  const size_t o_cnt = 0;
  const size_t o_wl  = 64;
  const size_t o_xh  = o_wl  + (size_t)WL_CAP * 4;         //  4 MiB
  const size_t o_xl  = o_xh  + (size_t)BS * DIN * 2;       //  4 MiB
  const size_t o_wsm = o_xl  + (size_t)BS * DIN * 2;       // 44 MiB (NCOL2 fp16)
  const size_t o_wh  = o_wsm + (size_t)NCOL2 * DIN * 2;    // 20 MiB
  const size_t o_wlo = o_wh  + (size_t)NLG * DIN * 2;      // 20 MiB
  const size_t o_wlt = o_wlo + (size_t)NLG * DIN * 2;      // 40 MiB (fp32 logit W^T)
  const size_t o_p   = o_wlt + (size_t)NLG * DIN * 4;      // 88 MiB (fp16 P2)
  const size_t o_lg  = o_p   + (size_t)BS * NCOL2 * 2;     // 84 MiB
  const size_t need  = o_lg  + (size_t)BS * NLG * 4;       // ~308 MiB total

  bool have_wl = ws_size >= 1024 * 1024;
  unsigned* cnt = (unsigned*)((char*)d_ws + o_cnt);
  unsigned* wl  = (unsigned*)((char*)d_ws + o_wl);
  unsigned cap  = 0;
  if (have_wl) {
    size_t avail = (ws_size >= need) ? (size_t)WL_CAP
                                     : (ws_size - o_wl) / 4;
    cap = (unsigned)(avail < WL_CAP ? avail : WL_CAP);
  }

  if (ws_size >= need) {
    half_t* xh  = (half_t*)((char*)d_ws + o_xh);
    half_t* xl  = (half_t*)((char*)d_ws + o_xl);
    half_t* wsm = (half_t*)((char*)d_ws + o_wsm);
    half_t* wh  = (half_t*)((char*)d_ws + o_wh);
    half_t* wlo = (half_t*)((char*)d_ws + o_wlo);
    float*  wlt = (float*)((char*)d_ws + o_wlt);
    half_t* P   = (half_t*)((char*)d_ws + o_p);
    float*  Lg  = (float*)((char*)d_ws + o_lg);

    k_prep<<<NB_SPLIT + NB_NORM + NB_TRW, 256, 0, stream>>>(x, xh, xl, nW, pW,
                                                            wsm, wh, wlo, wlt, cnt);
    k_gemm2<<<GEMM_BLKS, 512, 0, stream>>>(xh, xl, wh, wlo, wsm, Lg, P, pb, nb);
    k_pointwise<<<dim3(BS, DOUT / 256), 256, 0, stream>>>(P, Lg, t, out, cnt,
                                                          have_wl ? wl : nullptr, cap);
    if (have_wl)
      k_redo<<<256, 256, 0, stream>>>(x, t, pW, pb, nW, nb, P, wlt, 1, cnt, wl, cap, out);
  } else {
    if (have_wl) k_zero<<<1, 64, 0, stream>>>(cnt);
    k_naive<<<dim3(BS, DOUT / 256), 256, 0, stream>>>(x, t, pW, pb, nW, nb, out, cnt,
                                                      have_wl ? wl : nullptr, cap);
    if (have_wl)
      k_redo<<<256, 256, 0, stream>>>(x, t, pW, pb, nW, nb, nullptr, nullptr, 0,
                                      cnt, wl, cap, out);
  }
}